// Round 3
// baseline (1643.585 us; speedup 1.0000x reference)
//
#include <hip/hip_runtime.h>
#include <stdint.h>

#define B_ROWS 16384
#define E_DIM 1024
#define H_N 16

typedef unsigned short u16;
typedef __attribute__((ext_vector_type(4))) float f32x4;
typedef __attribute__((ext_vector_type(4))) unsigned short u16x4;
typedef __attribute__((ext_vector_type(8))) short bf16x8;

static __device__ __forceinline__ u16 f2bf(float f) {
  union { float f; unsigned u; } x; x.f = f;
  unsigned r = (x.u + 0x7FFFu + ((x.u >> 16) & 1u)) >> 16;
  return (u16)r;
}
static __device__ __forceinline__ float bf2f(u16 h) {
  union { unsigned u; float f; } x; x.u = ((unsigned)h) << 16;
  return x.f;
}

typedef const __attribute__((address_space(1))) void gvoid;
typedef __attribute__((address_space(3))) void lvoid;
static __device__ __forceinline__ void gload16(const void* g, void* l) {
  __builtin_amdgcn_global_load_lds((gvoid*)g, (lvoid*)l, 16, 0, 0);
}

// ---------------- f32 -> bf16 convert ----------------
__global__ __launch_bounds__(256) void cvt_f32_bf16(const float* __restrict__ in,
                                                    u16* __restrict__ out, int n4) {
  int stride = gridDim.x * blockDim.x;
  for (int i = blockIdx.x * blockDim.x + threadIdx.x; i < n4; i += stride) {
    f32x4 v = ((const f32x4*)in)[i];
    u16x4 o;
    o.x = f2bf(v.x); o.y = f2bf(v.y); o.z = f2bf(v.z); o.w = f2bf(v.w);
    ((u16x4*)out)[i] = o;
  }
}

// ---------------- transpose f32 [n x n] -> bf16 [n x n]^T ----------------
__global__ __launch_bounds__(256) void transpose_to_bf16(const float* __restrict__ in,
                                                         u16* __restrict__ out, int n) {
  __shared__ float t[32][33];
  int bx = blockIdx.x * 32;
  int by = blockIdx.y * 32;
  int tx = threadIdx.x, ty = threadIdx.y;  // 32 x 8
  for (int r = ty; r < 32; r += 8)
    t[r][tx] = in[(size_t)(by + r) * n + bx + tx];
  __syncthreads();
  for (int r = ty; r < 32; r += 8)
    out[(size_t)(bx + r) * n + by + tx] = f2bf(t[tx][r]);
}

// ---------------- folded bias: cb[j] = b_fuse[j] + sum_f sum_i b_out_f[i]*w_fuse[j, f*E+i]
__global__ __launch_bounds__(256) void fold_bias(const float* __restrict__ b0,
                                                 const float* __restrict__ b1,
                                                 const float* __restrict__ b2,
                                                 const float* __restrict__ wfuse,
                                                 const float* __restrict__ bfuse,
                                                 float* __restrict__ cb) {
  int wave = threadIdx.x >> 6, lane = threadIdx.x & 63;
  int j = blockIdx.x * 4 + wave;
  const float* wrow = wfuse + (size_t)j * (3 * E_DIM);
  float s = 0.f;
  for (int i = lane; i < E_DIM; i += 64) s += b0[i] * wrow[i];
  for (int i = lane; i < E_DIM; i += 64) s += b1[i] * wrow[E_DIM + i];
  for (int i = lane; i < E_DIM; i += 64) s += b2[i] * wrow[2 * E_DIM + i];
  for (int off = 32; off; off >>= 1) s += __shfl_xor(s, off);
  if (lane == 0) cb[j] = bfuse[j] + s;
}

// ---------------- concat bias for merged projection: [bq_j ; bkv_o0 ; bkv_o1] ----
__global__ __launch_bounds__(256) void concat_bias(const float* __restrict__ bq,
                                                   const float* __restrict__ bo0,
                                                   const float* __restrict__ bo1,
                                                   float* __restrict__ out) {
  int i = blockIdx.x * 256 + threadIdx.x;  // 5120 total
  float v;
  if (i < 1024) v = bq[i];
  else if (i < 3072) v = bo0[i];            // b_in_o0[E + (i-E)] == b_in_o0[i]
  else v = bo1[i - 2048];                   // b_in_o1[E + (i-3E)]
  out[i] = v;
}

// ---------------- GEMM: C[m,n] = sum_k A[m,k]*W[n,k] (+bias[n]) ----------------
// 2-phase prefetch (T3-minimum): double-buffered LDS, prefetch issued before
// compute, ONE barrier per K-step. T1 bijective XCD swizzle. T5 setprio.
// MODE 0: C bf16 = acc + bias(optional);  MODE 1: C f32 = acc + bias
#define BM 128
#define BN 128
#define BK 64

template <int MODE>
__global__ __launch_bounds__(256) void gemm_nt(const u16* __restrict__ A,
                                               const u16* __restrict__ W,
                                               void* __restrict__ Cp,
                                               const float* __restrict__ bias,
                                               int lda, int ldw, int ldc, int K, int nbn) {
  __shared__ __align__(16) u16 As[2][BM * BK];
  __shared__ __align__(16) u16 Bs[2][BN * BK];

  const int tid = threadIdx.x;
  const int wave = tid >> 6;
  const int lane = tid & 63;
  const int wm = wave >> 1;       // 2x2 wave grid, each wave owns 64x64
  const int wn = wave & 1;
  const int l16 = lane & 15;
  const int kq = lane >> 4;       // 0..3

  // T1: bijective XCD-aware block swizzle (m204 form, any nwg)
  const int nwg = gridDim.x;
  int bid = blockIdx.x;
  int xcd = bid & 7, orig = bid >> 3;
  int q8 = nwg >> 3, r8 = nwg & 7;
  int wg = (xcd < r8 ? xcd * (q8 + 1) : r8 * (q8 + 1) + (xcd - r8) * q8) + orig;
  const int bm = wg / nbn;
  const int bn = wg % nbn;

  const int srow = lane >> 3;          // 0..7 row within 8-row chunk
  const int scol = (lane & 7) * 8;     // col start (8 bf16 = 16B)

  const u16* Abase = A + (size_t)bm * BM * lda + scol;
  const u16* Wbase = W + (size_t)bn * BN * ldw + scol;

  f32x4 acc[4][4];
#pragma unroll
  for (int i = 0; i < 4; i++)
#pragma unroll
    for (int j = 0; j < 4; j++) acc[i][j] = (f32x4){0.f, 0.f, 0.f, 0.f};

  auto stage = [&](int buf, int k0) {
#pragma unroll
    for (int i = 0; i < 4; i++) {
      int c = wave * 4 + i;                 // chunk 0..15, 8 rows each
      int row = c * 8 + srow;
      gload16(Abase + (size_t)row * lda + k0, &As[buf][c * 512]);
    }
#pragma unroll
    for (int i = 0; i < 4; i++) {
      int c = wave * 4 + i;
      int row = c * 8 + srow;
      gload16(Wbase + (size_t)row * ldw + k0, &Bs[buf][c * 512]);
    }
  };

  const int nt = K / BK;
  stage(0, 0);
  __syncthreads();
  int cur = 0;
  for (int t = 0; t < nt; ++t) {
    if (t + 1 < nt) stage(cur ^ 1, (t + 1) * BK);   // prefetch overlaps compute
#pragma unroll
    for (int kk = 0; kk < 2; kk++) {
      bf16x8 af[4], bf[4];
#pragma unroll
      for (int mi = 0; mi < 4; mi++)
        af[mi] = *(const bf16x8*)&As[cur][(wm * 64 + mi * 16 + l16) * BK + kk * 32 + kq * 8];
#pragma unroll
      for (int ni = 0; ni < 4; ni++)
        bf[ni] = *(const bf16x8*)&Bs[cur][(wn * 64 + ni * 16 + l16) * BK + kk * 32 + kq * 8];
      __builtin_amdgcn_s_setprio(1);
#pragma unroll
      for (int mi = 0; mi < 4; mi++)
#pragma unroll
        for (int ni = 0; ni < 4; ni++)
          acc[mi][ni] = __builtin_amdgcn_mfma_f32_16x16x32_bf16(af[mi], bf[ni], acc[mi][ni], 0, 0, 0);
      __builtin_amdgcn_s_setprio(0);
    }
    __syncthreads();   // drains prefetch (vmcnt 0) + ds reads; next tile ready
    cur ^= 1;
  }

  const int r0 = kq * 4;  // C/D layout: col = lane&15, row = (lane>>4)*4 + r
#pragma unroll
  for (int mi = 0; mi < 4; mi++) {
#pragma unroll
    for (int ni = 0; ni < 4; ni++) {
      int row = bm * BM + wm * 64 + mi * 16 + r0;
      int col = bn * BN + wn * 64 + ni * 16 + l16;
      if (MODE == 0) {
        u16* C = (u16*)Cp;
        float bv = bias ? bias[col] : 0.f;
#pragma unroll
        for (int r = 0; r < 4; r++)
          C[(size_t)(row + r) * ldc + col] = f2bf(acc[mi][ni][r] + bv);
      } else {
        float* C = (float*)Cp;
        float bv = bias[col];
#pragma unroll
        for (int r = 0; r < 4; r++)
          C[(size_t)(row + r) * ldc + col] = acc[mi][ni][r] + bv;
      }
    }
  }
}

// ---------------- attention combine (merged-projection layout) ----------------
// P rows are 5120 wide: [Q(1024) | KV for o0 (2048) | KV for o1 (2048)].
// For this MHA: Q from Pq col d; K1/V1 from Pa cols offA+d / offA+1024+d;
// K2/V2 from Pb cols offB+d / offB+1024+d. Writes Oc[b*3072 + d].
__global__ __launch_bounds__(256) void attn_combine(const u16* __restrict__ Pq,
                                                    const u16* __restrict__ Pa,
                                                    const u16* __restrict__ Pb,
                                                    int offA, int offB,
                                                    u16* __restrict__ Oc) {
  int gw = blockIdx.x * 4 + (threadIdx.x >> 6);
  int lane = threadIdx.x & 63;
  int b = gw >> 4, h = gw & 15;
  int d = h * 64 + lane;
  size_t prow = (size_t)b * 5120;
  float q = bf2f(Pq[prow + d]);
  float k1 = bf2f(Pa[prow + offA + d]);
  float v1 = bf2f(Pa[prow + offA + 1024 + d]);
  float k2 = bf2f(Pb[prow + offB + d]);
  float v2 = bf2f(Pb[prow + offB + 1024 + d]);
  float s1 = q * k1, s2 = q * k2;
  for (int off = 32; off; off >>= 1) {
    s1 += __shfl_xor(s1, off);
    s2 += __shfl_xor(s2, off);
  }
  s1 *= 0.125f; s2 *= 0.125f;  // 1/sqrt(64)
  float m = fmaxf(s1, s2);
  float e1 = __expf(s1 - m), e2 = __expf(s2 - m);
  float rn = 1.f / (e1 + e2);
  Oc[(size_t)b * 3072 + d] = f2bf((e1 * rn) * v1 + (e2 * rn) * v2);
}

// ---------------- layernorm in place on f32 [B,1024] ----------------
__global__ __launch_bounds__(256) void layernorm_inplace(float* __restrict__ y,
                                                         const float* __restrict__ g,
                                                         const float* __restrict__ b) {
  int row = blockIdx.x, tid = threadIdx.x;
  float* yr = y + (size_t)row * E_DIM;
  f32x4 v = ((const f32x4*)yr)[tid];
  float s = v.x + v.y + v.z + v.w;
  float sq = v.x * v.x + v.y * v.y + v.z * v.z + v.w * v.w;
  for (int off = 32; off; off >>= 1) {
    s += __shfl_xor(s, off);
    sq += __shfl_xor(sq, off);
  }
  __shared__ float rs[4], rq[4];
  int wave = tid >> 6, lane = tid & 63;
  if (lane == 0) { rs[wave] = s; rq[wave] = sq; }
  __syncthreads();
  s = rs[0] + rs[1] + rs[2] + rs[3];
  sq = rq[0] + rq[1] + rq[2] + rq[3];
  float mu = s * (1.f / E_DIM);
  float var = sq * (1.f / E_DIM) - mu * mu;
  float rstd = rsqrtf(var + 1e-5f);
  f32x4 gg = ((const f32x4*)g)[tid];
  f32x4 bb = ((const f32x4*)b)[tid];
  f32x4 o;
  o.x = (v.x - mu) * rstd * gg.x + bb.x;
  o.y = (v.y - mu) * rstd * gg.y + bb.y;
  o.z = (v.z - mu) * rstd * gg.z + bb.z;
  o.w = (v.w - mu) * rstd * gg.w + bb.w;
  ((f32x4*)yr)[tid] = o;
}

extern "C" void kernel_launch(void* const* d_in, const int* in_sizes, int n_in,
                              void* d_out, int out_size, void* d_ws, size_t ws_size,
                              hipStream_t stream) {
  const float* feat[3] = {(const float*)d_in[0], (const float*)d_in[1], (const float*)d_in[2]};
  const float* w_in[3] = {(const float*)d_in[3], (const float*)d_in[7], (const float*)d_in[11]};
  const float* b_in[3] = {(const float*)d_in[4], (const float*)d_in[8], (const float*)d_in[12]};
  const float* w_out[3] = {(const float*)d_in[5], (const float*)d_in[9], (const float*)d_in[13]};
  const float* b_out[3] = {(const float*)d_in[6], (const float*)d_in[10], (const float*)d_in[14]};
  const float* w_fuse = (const float*)d_in[15];
  const float* b_fuse = (const float*)d_in[16];
  const float* ln_g = (const float*)d_in[17];
  const float* ln_b = (const float*)d_in[18];

  auto A256 = [](size_t b) { return (b + 255) & ~(size_t)255; };
  const size_t EE = (size_t)E_DIM * E_DIM;

  // Persistent: Wcat[3] (5E x E bf16), bcat[3] (5E f32), Mcat (E x 3E bf16), cb (E f32)
  const size_t persist = 3 * A256(5 * EE * 2) + 3 * A256(5 * E_DIM * 4) +
                         A256(3 * EE * 2) + A256(E_DIM * 4);

  // Per-row pool: fb[3] (E bf16 each) + P[3] (5E bf16 each) + Ocat (3E bf16)
  // = 3*2048 + 3*10240 + 6144 = 43008 B/row. Pick largest CH (mult of 256).
  int CH = B_ROWS;
  while (CH > 256) {
    size_t pool = 3 * A256((size_t)CH * E_DIM * 2) + 3 * A256((size_t)CH * 5 * E_DIM * 2) +
                  A256((size_t)CH * 3 * E_DIM * 2);
    if (persist + pool <= ws_size) break;
    CH -= 256;
  }

  char* p = (char*)d_ws;
  auto alloc = [&](size_t bytes) {
    void* r = (void*)p;
    p += A256(bytes);
    return r;
  };

  u16* Wcat[3];
  for (int i = 0; i < 3; i++) Wcat[i] = (u16*)alloc(5 * EE * 2);
  float* bcat[3];
  for (int i = 0; i < 3; i++) bcat[i] = (float*)alloc(5 * E_DIM * 4);
  u16* Mcat = (u16*)alloc(3 * EE * 2);
  float* cb = (float*)alloc(E_DIM * 4);

  char* pool = p;  // transient region, reused between stage 1 and stage 2

  const int oth[3][2] = {{1, 2}, {0, 2}, {0, 1}};  // sorted others(j)

  // ---- stage 0: build Wcat_j = [wq_j ; wkv_o0 ; wkv_o1] (bf16) + bcat_j ----
  for (int j = 0; j < 3; j++) {
    int o0 = oth[j][0], o1 = oth[j][1];
    cvt_f32_bf16<<<256, 256, 0, stream>>>(w_in[j], Wcat[j], (int)(EE / 4));
    cvt_f32_bf16<<<512, 256, 0, stream>>>(w_in[o0] + EE, Wcat[j] + EE, (int)(2 * EE / 4));
    cvt_f32_bf16<<<512, 256, 0, stream>>>(w_in[o1] + EE, Wcat[j] + 3 * EE, (int)(2 * EE / 4));
    concat_bias<<<5 * E_DIM / 256, 256, 0, stream>>>(b_in[j], b_in[o0], b_in[o1], bcat[j]);
  }

  // ---- stage 1: Mcat[:, m*E + i] = (w_fuse[:, mE:(m+1)E] @ w_out_m)[:, i]; cb ----
  {
    u16* wfusebf = (u16*)pool;
    u16* woutT = (u16*)(pool + A256(3 * EE * 2));
    cvt_f32_bf16<<<1024, 256, 0, stream>>>(w_fuse, wfusebf, (int)(3 * EE / 4));
    dim3 tb(32, 8);
    for (int f = 0; f < 3; f++) {
      transpose_to_bf16<<<dim3(E_DIM / 32, E_DIM / 32), tb, 0, stream>>>(w_out[f], woutT, E_DIM);
      gemm_nt<0><<<(E_DIM / BM) * (E_DIM / BN), 256, 0, stream>>>(
          wfusebf + f * E_DIM, woutT, (void*)(Mcat + f * E_DIM), nullptr,
          3 * E_DIM, E_DIM, 3 * E_DIM, E_DIM, E_DIM / BN);
    }
    fold_bias<<<E_DIM / 4, 256, 0, stream>>>(b_out[0], b_out[1], b_out[2], w_fuse, b_fuse, cb);
  }

  // ---- stage 2: chunk loop ----
  {
    char* q = pool;
    auto palloc = [&](size_t bytes) {
      void* r = (void*)q;
      q += A256(bytes);
      return r;
    };
    u16* fb[3];
    for (int i = 0; i < 3; i++) fb[i] = (u16*)palloc((size_t)CH * E_DIM * 2);
    u16* P[3];
    for (int i = 0; i < 3; i++) P[i] = (u16*)palloc((size_t)CH * 5 * E_DIM * 2);
    u16* Ocat = (u16*)palloc((size_t)CH * 3 * E_DIM * 2);

    // combine tables: for MHA m, kv feats (j1,j2); column offset of m's KV block
    // within P[j] is E + rank*2E where rank = (m != min(others(j))).
    const int j1a[3] = {1, 0, 0}, j2a[3] = {2, 2, 1};
    const int offA[3] = {1024, 1024, 3072}, offB[3] = {1024, 3072, 3072};

    for (int row0 = 0; row0 < B_ROWS; row0 += CH) {
      int rows = B_ROWS - row0 < CH ? B_ROWS - row0 : CH;
      for (int j = 0; j < 3; j++)
        cvt_f32_bf16<<<1024, 256, 0, stream>>>(feat[j] + (size_t)row0 * E_DIM, fb[j],
                                               rows * (E_DIM / 4));
      // merged projection: P[j] = fb[j] @ Wcat_j^T + bcat_j   [rows, 5120]
      for (int j = 0; j < 3; j++)
        gemm_nt<0><<<(rows / BM) * (5 * E_DIM / BN), 256, 0, stream>>>(
            fb[j], Wcat[j], (void*)P[j], bcat[j], E_DIM, E_DIM, 5 * E_DIM, E_DIM,
            5 * E_DIM / BN);
      // softmax-combine into Ocat[:, m*E:(m+1)E]
      for (int m = 0; m < 3; m++)
        attn_combine<<<rows * H_N / 4, 256, 0, stream>>>(
            P[m], P[j1a[m]], P[j2a[m]], offA[m], offB[m], Ocat + m * E_DIM);
      // final: y = Ocat @ Mcat^T + cb   (K = 3072, f32 out)
      gemm_nt<1><<<(rows / BM) * (E_DIM / BN), 256, 0, stream>>>(
          Ocat, Mcat, (void*)((float*)d_out + (size_t)row0 * E_DIM), cb,
          3 * E_DIM, 3 * E_DIM, E_DIM, 3 * E_DIM, E_DIM / BN);
    }
  }

  // ---- stage 3: layernorm in place on d_out ----
  layernorm_inplace<<<B_ROWS, 256, 0, stream>>>((float*)d_out, ln_g, ln_b);
}

// Round 4
// 1361.228 us; speedup vs baseline: 1.2074x; 1.2074x over previous
//
#include <hip/hip_runtime.h>
#include <stdint.h>

#define B_ROWS 16384
#define E_DIM 1024
#define H_N 16

typedef unsigned short u16;
typedef __attribute__((ext_vector_type(4))) float f32x4;
typedef __attribute__((ext_vector_type(4))) unsigned short u16x4;
typedef __attribute__((ext_vector_type(8))) short bf16x8;

static __device__ __forceinline__ u16 f2bf(float f) {
  union { float f; unsigned u; } x; x.f = f;
  unsigned r = (x.u + 0x7FFFu + ((x.u >> 16) & 1u)) >> 16;
  return (u16)r;
}
static __device__ __forceinline__ float bf2f(u16 h) {
  union { unsigned u; float f; } x; x.u = ((unsigned)h) << 16;
  return x.f;
}

typedef const __attribute__((address_space(1))) void gvoid;
typedef __attribute__((address_space(3))) void lvoid;
static __device__ __forceinline__ void gload16(const void* g, void* l) {
  __builtin_amdgcn_global_load_lds((gvoid*)g, (lvoid*)l, 16, 0, 0);
}

// ---------------- f32 -> bf16 convert ----------------
__global__ __launch_bounds__(256) void cvt_f32_bf16(const float* __restrict__ in,
                                                    u16* __restrict__ out, int n4) {
  int stride = gridDim.x * blockDim.x;
  for (int i = blockIdx.x * blockDim.x + threadIdx.x; i < n4; i += stride) {
    f32x4 v = ((const f32x4*)in)[i];
    u16x4 o;
    o.x = f2bf(v.x); o.y = f2bf(v.y); o.z = f2bf(v.z); o.w = f2bf(v.w);
    ((u16x4*)out)[i] = o;
  }
}

// ---------------- transpose f32 [n x n] -> bf16 [n x n]^T ----------------
__global__ __launch_bounds__(256) void transpose_to_bf16(const float* __restrict__ in,
                                                         u16* __restrict__ out, int n) {
  __shared__ float t[32][33];
  int bx = blockIdx.x * 32;
  int by = blockIdx.y * 32;
  int tx = threadIdx.x, ty = threadIdx.y;  // 32 x 8
  for (int r = ty; r < 32; r += 8)
    t[r][tx] = in[(size_t)(by + r) * n + bx + tx];
  __syncthreads();
  for (int r = ty; r < 32; r += 8)
    out[(size_t)(bx + r) * n + by + tx] = f2bf(t[tx][r]);
}

// ---------------- folded bias: cb[j] = b_fuse[j] + sum_f sum_i b_out_f[i]*w_fuse[j, f*E+i]
__global__ __launch_bounds__(256) void fold_bias(const float* __restrict__ b0,
                                                 const float* __restrict__ b1,
                                                 const float* __restrict__ b2,
                                                 const float* __restrict__ wfuse,
                                                 const float* __restrict__ bfuse,
                                                 float* __restrict__ cb) {
  int wave = threadIdx.x >> 6, lane = threadIdx.x & 63;
  int j = blockIdx.x * 4 + wave;
  const float* wrow = wfuse + (size_t)j * (3 * E_DIM);
  float s = 0.f;
  for (int i = lane; i < E_DIM; i += 64) s += b0[i] * wrow[i];
  for (int i = lane; i < E_DIM; i += 64) s += b1[i] * wrow[E_DIM + i];
  for (int i = lane; i < E_DIM; i += 64) s += b2[i] * wrow[2 * E_DIM + i];
  for (int off = 32; off; off >>= 1) s += __shfl_xor(s, off);
  if (lane == 0) cb[j] = bfuse[j] + s;
}

// ---------------- concat bias for merged projection: [bq_j ; bkv_o0 ; bkv_o1] ----
__global__ __launch_bounds__(256) void concat_bias(const float* __restrict__ bq,
                                                   const float* __restrict__ bo0,
                                                   const float* __restrict__ bo1,
                                                   float* __restrict__ out) {
  int i = blockIdx.x * 256 + threadIdx.x;  // 5120 total
  float v;
  if (i < 1024) v = bq[i];
  else if (i < 3072) v = bo0[i];
  else v = bo1[i - 2048];
  out[i] = v;
}

// ================= GEMM: C[m,n] = sum_k A[m,k]*W[n,k] (+bias[n]) =================
// 128x256x64 tile, 8 waves (2M x 4N, 64x64 per wave), 3-buffer LDS ring,
// prefetch distance 2 K-tiles, counted s_waitcnt vmcnt(6) (T4), raw s_barrier,
// XOR-swizzled LDS (T2, via pre-swizzled global source), setprio (T5),
// bijective XCD swizzle (T1).
// MODE 0: C bf16 = acc + bias(optional);  MODE 1: C f32 = acc + bias
#define BM 128
#define BN 256
#define BK 64
#define TILE_EL ((BM + BN) * BK)   // 24576 u16 per buffer (A:8192, B:16384)

template <int MODE>
__global__ __launch_bounds__(512, 2) void gemm_nt(const u16* __restrict__ A,
                                                  const u16* __restrict__ W,
                                                  void* __restrict__ Cp,
                                                  const float* __restrict__ bias,
                                                  int lda, int ldw, int ldc, int K, int nbn) {
  __shared__ __align__(16) u16 lds[3][TILE_EL];

  const int tid = threadIdx.x;
  const int wave = tid >> 6;
  const int lane = tid & 63;
  const int wm = wave >> 2;       // 0..1  (row group, 64 rows each)
  const int wn = wave & 3;        // 0..3  (col group, 64 cols each)
  const int l16 = lane & 15;
  const int kq = lane >> 4;       // 0..3
  const int sw8 = (l16 & 7) << 4; // read-side XOR swizzle (bytes)

  // T1: bijective XCD-aware block swizzle
  const int nwg = gridDim.x;
  int bid = blockIdx.x;
  int xcd = bid & 7, orig = bid >> 3;
  int q8 = nwg >> 3, r8 = nwg & 7;
  int wg = (xcd < r8 ? xcd * (q8 + 1) : r8 * (q8 + 1) + (xcd - r8) * q8) + orig;
  const int bm = wg / nbn;
  const int bn = wg % nbn;

  const u16* Abase = A + (size_t)bm * BM * lda;
  const u16* Wbase = W + (size_t)bn * BN * ldw;

  f32x4 acc[4][4];
#pragma unroll
  for (int i = 0; i < 4; i++)
#pragma unroll
    for (int j = 0; j < 4; j++) acc[i][j] = (f32x4){0.f, 0.f, 0.f, 0.f};

  // Stage one K-tile into buffer `buf`. Linear LDS dest (wave-uniform base +
  // lane*16), pre-swizzled global source: LDS(row, s) = global(row, s ^ ((row&7)<<4)).
  auto stage = [&](int buf, int k0) {
#pragma unroll
    for (int r = 0; r < 2; r++) {                      // A: 128 rows x 64 cols
      int row = r * 64 + (tid >> 3);
      int colel = (((tid & 7) << 4) ^ ((row & 7) << 4)) >> 1;
      gload16(Abase + (size_t)row * lda + k0 + colel, &lds[buf][(r * 512 + tid) * 8]);
    }
#pragma unroll
    for (int r = 0; r < 4; r++) {                      // B: 256 rows x 64 cols
      int row = r * 64 + (tid >> 3);
      int colel = (((tid & 7) << 4) ^ ((row & 7) << 4)) >> 1;
      gload16(Wbase + (size_t)row * ldw + k0 + colel, &lds[buf][BM * BK + (r * 512 + tid) * 8]);
    }
  };

  const int nt = K / BK;
  // prologue: stage tiles 0,1; wait tile 0 landed (6 newest = tile 1 may float)
  stage(0, 0);
  stage(1, BK);
  asm volatile("s_waitcnt vmcnt(6)" ::: "memory");
  __builtin_amdgcn_s_barrier();
  __builtin_amdgcn_sched_barrier(0);

  int cur = 0;
  for (int t = 0; t < nt; ++t) {
    const bool pf = (t + 2 < nt);
    if (pf) {
      int st = cur + 2; if (st >= 3) st -= 3;
      stage(st, (t + 2) * BK);                 // targets buffer freed at end of t-1
    }
    const u16* As = &lds[cur][0];
    const u16* Bs = &lds[cur][BM * BK];
#pragma unroll
    for (int kk = 0; kk < 2; kk++) {
      const int cb = ((kk * 64 + kq * 16) ^ sw8) >> 1;  // swizzled col (elements)
      bf16x8 af[4], bfr[4];
#pragma unroll
      for (int mi = 0; mi < 4; mi++)
        af[mi] = *(const bf16x8*)&As[(wm * 64 + mi * 16 + l16) * BK + cb];
#pragma unroll
      for (int ni = 0; ni < 4; ni++)
        bfr[ni] = *(const bf16x8*)&Bs[(wn * 64 + ni * 16 + l16) * BK + cb];
      __builtin_amdgcn_s_setprio(1);
#pragma unroll
      for (int mi = 0; mi < 4; mi++)
#pragma unroll
        for (int ni = 0; ni < 4; ni++)
          acc[mi][ni] = __builtin_amdgcn_mfma_f32_16x16x32_bf16(af[mi], bfr[ni], acc[mi][ni], 0, 0, 0);
      __builtin_amdgcn_s_setprio(0);
    }
    // counted wait: everything older than the 6 loads issued THIS tile has landed
    // => tile t+1 is resident before any wave reads it after the barrier.
    if (pf) asm volatile("s_waitcnt vmcnt(6)" ::: "memory");
    else    asm volatile("s_waitcnt vmcnt(0)" ::: "memory");
    __builtin_amdgcn_s_barrier();
    __builtin_amdgcn_sched_barrier(0);
    cur = cur + 1 == 3 ? 0 : cur + 1;
  }

  const int r0 = kq * 4;  // C/D: col = lane&15, row = (lane>>4)*4 + r
#pragma unroll
  for (int mi = 0; mi < 4; mi++) {
#pragma unroll
    for (int ni = 0; ni < 4; ni++) {
      int row = bm * BM + wm * 64 + mi * 16 + r0;
      int col = bn * BN + wn * 64 + ni * 16 + l16;
      if (MODE == 0) {
        u16* C = (u16*)Cp;
        float bv = bias ? bias[col] : 0.f;
#pragma unroll
        for (int r = 0; r < 4; r++)
          C[(size_t)(row + r) * ldc + col] = f2bf(acc[mi][ni][r] + bv);
      } else {
        float* C = (float*)Cp;
        float bv = bias[col];
#pragma unroll
        for (int r = 0; r < 4; r++)
          C[(size_t)(row + r) * ldc + col] = acc[mi][ni][r] + bv;
      }
    }
  }
}

// ---------------- attention combine (merged-projection layout) ----------------
__global__ __launch_bounds__(256) void attn_combine(const u16* __restrict__ Pq,
                                                    const u16* __restrict__ Pa,
                                                    const u16* __restrict__ Pb,
                                                    int offA, int offB,
                                                    u16* __restrict__ Oc) {
  int gw = blockIdx.x * 4 + (threadIdx.x >> 6);
  int lane = threadIdx.x & 63;
  int b = gw >> 4, h = gw & 15;
  int d = h * 64 + lane;
  size_t prow = (size_t)b * 5120;
  float q = bf2f(Pq[prow + d]);
  float k1 = bf2f(Pa[prow + offA + d]);
  float v1 = bf2f(Pa[prow + offA + 1024 + d]);
  float k2 = bf2f(Pb[prow + offB + d]);
  float v2 = bf2f(Pb[prow + offB + 1024 + d]);
  float s1 = q * k1, s2 = q * k2;
  for (int off = 32; off; off >>= 1) {
    s1 += __shfl_xor(s1, off);
    s2 += __shfl_xor(s2, off);
  }
  s1 *= 0.125f; s2 *= 0.125f;  // 1/sqrt(64)
  float m = fmaxf(s1, s2);
  float e1 = __expf(s1 - m), e2 = __expf(s2 - m);
  float rn = 1.f / (e1 + e2);
  Oc[(size_t)b * 3072 + d] = f2bf((e1 * rn) * v1 + (e2 * rn) * v2);
}

// ---------------- layernorm in place on f32 [B,1024] ----------------
__global__ __launch_bounds__(256) void layernorm_inplace(float* __restrict__ y,
                                                         const float* __restrict__ g,
                                                         const float* __restrict__ b) {
  int row = blockIdx.x, tid = threadIdx.x;
  float* yr = y + (size_t)row * E_DIM;
  f32x4 v = ((const f32x4*)yr)[tid];
  float s = v.x + v.y + v.z + v.w;
  float sq = v.x * v.x + v.y * v.y + v.z * v.z + v.w * v.w;
  for (int off = 32; off; off >>= 1) {
    s += __shfl_xor(s, off);
    sq += __shfl_xor(sq, off);
  }
  __shared__ float rs[4], rq[4];
  int wave = tid >> 6, lane = tid & 63;
  if (lane == 0) { rs[wave] = s; rq[wave] = sq; }
  __syncthreads();
  s = rs[0] + rs[1] + rs[2] + rs[3];
  sq = rq[0] + rq[1] + rq[2] + rq[3];
  float mu = s * (1.f / E_DIM);
  float var = sq * (1.f / E_DIM) - mu * mu;
  float rstd = rsqrtf(var + 1e-5f);
  f32x4 gg = ((const f32x4*)g)[tid];
  f32x4 bb = ((const f32x4*)b)[tid];
  f32x4 o;
  o.x = (v.x - mu) * rstd * gg.x + bb.x;
  o.y = (v.y - mu) * rstd * gg.y + bb.y;
  o.z = (v.z - mu) * rstd * gg.z + bb.z;
  o.w = (v.w - mu) * rstd * gg.w + bb.w;
  ((f32x4*)yr)[tid] = o;
}

extern "C" void kernel_launch(void* const* d_in, const int* in_sizes, int n_in,
                              void* d_out, int out_size, void* d_ws, size_t ws_size,
                              hipStream_t stream) {
  const float* feat[3] = {(const float*)d_in[0], (const float*)d_in[1], (const float*)d_in[2]};
  const float* w_in[3] = {(const float*)d_in[3], (const float*)d_in[7], (const float*)d_in[11]};
  const float* b_in[3] = {(const float*)d_in[4], (const float*)d_in[8], (const float*)d_in[12]};
  const float* w_out[3] = {(const float*)d_in[5], (const float*)d_in[9], (const float*)d_in[13]};
  const float* b_out[3] = {(const float*)d_in[6], (const float*)d_in[10], (const float*)d_in[14]};
  const float* w_fuse = (const float*)d_in[15];
  const float* b_fuse = (const float*)d_in[16];
  const float* ln_g = (const float*)d_in[17];
  const float* ln_b = (const float*)d_in[18];

  auto A256 = [](size_t b) { return (b + 255) & ~(size_t)255; };
  const size_t EE = (size_t)E_DIM * E_DIM;

  const size_t persist = 3 * A256(5 * EE * 2) + 3 * A256(5 * E_DIM * 4) +
                         A256(3 * EE * 2) + A256(E_DIM * 4);

  int CH = B_ROWS;
  while (CH > 256) {
    size_t pool = 3 * A256((size_t)CH * E_DIM * 2) + 3 * A256((size_t)CH * 5 * E_DIM * 2) +
                  A256((size_t)CH * 3 * E_DIM * 2);
    if (persist + pool <= ws_size) break;
    CH -= 256;
  }

  char* p = (char*)d_ws;
  auto alloc = [&](size_t bytes) {
    void* r = (void*)p;
    p += A256(bytes);
    return r;
  };

  u16* Wcat[3];
  for (int i = 0; i < 3; i++) Wcat[i] = (u16*)alloc(5 * EE * 2);
  float* bcat[3];
  for (int i = 0; i < 3; i++) bcat[i] = (float*)alloc(5 * E_DIM * 4);
  u16* Mcat = (u16*)alloc(3 * EE * 2);
  float* cb = (float*)alloc(E_DIM * 4);

  char* pool = p;

  const int oth[3][2] = {{1, 2}, {0, 2}, {0, 1}};

  // ---- stage 0: Wcat_j = [wq_j ; wkv_o0 ; wkv_o1] (bf16) + bcat_j ----
  for (int j = 0; j < 3; j++) {
    int o0 = oth[j][0], o1 = oth[j][1];
    cvt_f32_bf16<<<256, 256, 0, stream>>>(w_in[j], Wcat[j], (int)(EE / 4));
    cvt_f32_bf16<<<512, 256, 0, stream>>>(w_in[o0] + EE, Wcat[j] + EE, (int)(2 * EE / 4));
    cvt_f32_bf16<<<512, 256, 0, stream>>>(w_in[o1] + EE, Wcat[j] + 3 * EE, (int)(2 * EE / 4));
    concat_bias<<<5 * E_DIM / 256, 256, 0, stream>>>(b_in[j], b_in[o0], b_in[o1], bcat[j]);
  }

  // ---- stage 1: Mcat[:, f*E:(f+1)E] = w_fuse[:, fE:(f+1)E] @ w_out_f ; cb ----
  {
    u16* wfusebf = (u16*)pool;
    u16* woutT = (u16*)(pool + A256(3 * EE * 2));
    cvt_f32_bf16<<<1024, 256, 0, stream>>>(w_fuse, wfusebf, (int)(3 * EE / 4));
    dim3 tb(32, 8);
    for (int f = 0; f < 3; f++) {
      transpose_to_bf16<<<dim3(E_DIM / 32, E_DIM / 32), tb, 0, stream>>>(w_out[f], woutT, E_DIM);
      gemm_nt<0><<<(E_DIM / BM) * (E_DIM / BN), 512, 0, stream>>>(
          wfusebf + f * E_DIM, woutT, (void*)(Mcat + f * E_DIM), nullptr,
          3 * E_DIM, E_DIM, 3 * E_DIM, E_DIM, E_DIM / BN);
    }
    fold_bias<<<E_DIM / 4, 256, 0, stream>>>(b_out[0], b_out[1], b_out[2], w_fuse, b_fuse, cb);
  }

  // ---- stage 2: chunk loop ----
  {
    char* q = pool;
    auto palloc = [&](size_t bytes) {
      void* r = (void*)q;
      q += A256(bytes);
      return r;
    };
    u16* fb[3];
    for (int i = 0; i < 3; i++) fb[i] = (u16*)palloc((size_t)CH * E_DIM * 2);
    u16* P[3];
    for (int i = 0; i < 3; i++) P[i] = (u16*)palloc((size_t)CH * 5 * E_DIM * 2);
    u16* Ocat = (u16*)palloc((size_t)CH * 3 * E_DIM * 2);

    const int j1a[3] = {1, 0, 0}, j2a[3] = {2, 2, 1};
    const int offA[3] = {1024, 1024, 3072}, offB[3] = {1024, 3072, 3072};

    for (int row0 = 0; row0 < B_ROWS; row0 += CH) {
      int rows = B_ROWS - row0 < CH ? B_ROWS - row0 : CH;
      for (int j = 0; j < 3; j++)
        cvt_f32_bf16<<<1024, 256, 0, stream>>>(feat[j] + (size_t)row0 * E_DIM, fb[j],
                                               rows * (E_DIM / 4));
      for (int j = 0; j < 3; j++)
        gemm_nt<0><<<(rows / BM) * (5 * E_DIM / BN), 512, 0, stream>>>(
            fb[j], Wcat[j], (void*)P[j], bcat[j], E_DIM, E_DIM, 5 * E_DIM, E_DIM,
            5 * E_DIM / BN);
      for (int m = 0; m < 3; m++)
        attn_combine<<<rows * H_N / 4, 256, 0, stream>>>(
            P[m], P[j1a[m]], P[j2a[m]], offA[m], offB[m], Ocat + m * E_DIM);
      gemm_nt<1><<<(rows / BM) * (E_DIM / BN), 512, 0, stream>>>(
          Ocat, Mcat, (void*)((float*)d_out + (size_t)row0 * E_DIM), cb,
          3 * E_DIM, 3 * E_DIM, E_DIM, 3 * E_DIM, E_DIM / BN);
    }
  }

  // ---- stage 3: layernorm in place on d_out ----
  layernorm_inplace<<<B_ROWS, 256, 0, stream>>>((float*)d_out, ln_g, ln_b);
}

// Round 6
// 1152.857 us; speedup vs baseline: 1.4257x; 1.1807x over previous
//
#include <hip/hip_runtime.h>
#include <stdint.h>

#define B_ROWS 16384
#define E_DIM 1024
#define H_N 16

typedef unsigned short u16;
typedef __attribute__((ext_vector_type(4))) float f32x4;
typedef __attribute__((ext_vector_type(4))) unsigned short u16x4;
typedef __attribute__((ext_vector_type(8))) short bf16x8;

static __device__ __forceinline__ u16 f2bf(float f) {
  union { float f; unsigned u; } x; x.f = f;
  unsigned r = (x.u + 0x7FFFu + ((x.u >> 16) & 1u)) >> 16;
  return (u16)r;
}
static __device__ __forceinline__ float bf2f(u16 h) {
  union { unsigned u; float f; } x; x.u = ((unsigned)h) << 16;
  return x.f;
}

typedef const __attribute__((address_space(1))) void gvoid;
typedef __attribute__((address_space(3))) void lvoid;
static __device__ __forceinline__ void gload16(const void* g, void* l) {
  __builtin_amdgcn_global_load_lds((gvoid*)g, (lvoid*)l, 16, 0, 0);
}

// ---------------- f32 -> bf16 convert ----------------
__global__ __launch_bounds__(256) void cvt_f32_bf16(const float* __restrict__ in,
                                                    u16* __restrict__ out, int n4) {
  int stride = gridDim.x * blockDim.x;
  for (int i = blockIdx.x * blockDim.x + threadIdx.x; i < n4; i += stride) {
    f32x4 v = ((const f32x4*)in)[i];
    u16x4 o;
    o.x = f2bf(v.x); o.y = f2bf(v.y); o.z = f2bf(v.z); o.w = f2bf(v.w);
    ((u16x4*)out)[i] = o;
  }
}

// ---------------- transpose f32 [n x n] -> bf16 [n x n]^T ----------------
__global__ __launch_bounds__(256) void transpose_to_bf16(const float* __restrict__ in,
                                                         u16* __restrict__ out, int n) {
  __shared__ float t[32][33];
  int bx = blockIdx.x * 32;
  int by = blockIdx.y * 32;
  int tx = threadIdx.x, ty = threadIdx.y;  // 32 x 8
  for (int r = ty; r < 32; r += 8)
    t[r][tx] = in[(size_t)(by + r) * n + bx + tx];
  __syncthreads();
  for (int r = ty; r < 32; r += 8)
    out[(size_t)(bx + r) * n + by + tx] = f2bf(t[tx][r]);
}

// ---------------- folded bias ----------------
__global__ __launch_bounds__(256) void fold_bias(const float* __restrict__ b0,
                                                 const float* __restrict__ b1,
                                                 const float* __restrict__ b2,
                                                 const float* __restrict__ wfuse,
                                                 const float* __restrict__ bfuse,
                                                 float* __restrict__ cb) {
  int wave = threadIdx.x >> 6, lane = threadIdx.x & 63;
  int j = blockIdx.x * 4 + wave;
  const float* wrow = wfuse + (size_t)j * (3 * E_DIM);
  float s = 0.f;
  for (int i = lane; i < E_DIM; i += 64) s += b0[i] * wrow[i];
  for (int i = lane; i < E_DIM; i += 64) s += b1[i] * wrow[E_DIM + i];
  for (int i = lane; i < E_DIM; i += 64) s += b2[i] * wrow[2 * E_DIM + i];
  for (int off = 32; off; off >>= 1) s += __shfl_xor(s, off);
  if (lane == 0) cb[j] = bfuse[j] + s;
}

// ---------------- concat bias: [bq_j ; bkv_o0 ; bkv_o1] ----------------
__global__ __launch_bounds__(256) void concat_bias(const float* __restrict__ bq,
                                                   const float* __restrict__ bo0,
                                                   const float* __restrict__ bo1,
                                                   float* __restrict__ out) {
  int i = blockIdx.x * 256 + threadIdx.x;  // 5120 total
  float v;
  if (i < 1024) v = bq[i];
  else if (i < 3072) v = bo0[i];
  else v = bo1[i - 2048];
  out[i] = v;
}

// ================= GEMM 256x256x64, 8 waves, 4-phase/K-tile =================
// Per-wave output: 128 rows (wm half) x 64 cols SPLIT as qn*128 + wn*32 + [0..31]
// so RDB(qn) touches ONLY staging half B(qn) -- this aligns the read phases with
// the staging halves so the counted-vmcnt ledger covers every LDS read:
//   stage order per tile t (for t+1): Ph0:A0 Ph1:A1 Ph2:B0 Ph3:B1
//   end Ph0: vmcnt(2)  forces B1(t) resident  (B1 is only read in Ph1/Ph3)
//   end Ph3: vmcnt(2)  forces A0,A1,B0(t+1) resident (read in next Ph0/Ph2)
//   B1 never drained at tile boundary; max 8 loads in flight; tails vmcnt(0)/skip.
// LDS XOR-swizzle via pre-swizzled global source (involution; R4: conflicts=0).
#define BM 256
#define BN 256
#define BK 64

#define RDA(buf, qm, dst)                                                         \
  do {                                                                            \
    _Pragma("unroll") for (int m = 0; m < 4; m++)                                 \
    _Pragma("unroll") for (int kk = 0; kk < 2; kk++) {                            \
      int rl = (qm)*64 + m * 16 + l16; /* row within wave's 128-row half */       \
      int col = ((kk * 64 + kq * 16) ^ ((l16 & 7) << 4)) >> 1;                    \
      dst[m][kk] = *(const bf16x8*)&lds[buf][wm * 8192 + rl * 64 + col];          \
    }                                                                             \
  } while (0)

#define RDB(buf, qn, dst)                                                         \
  do {                                                                            \
    _Pragma("unroll") for (int n = 0; n < 2; n++)                                 \
    _Pragma("unroll") for (int kk = 0; kk < 2; kk++) {                            \
      int rt = (qn)*128 + wn * 32 + n * 16 + l16; /* B half = qn ONLY */          \
      int col = ((kk * 64 + kq * 16) ^ ((l16 & 7) << 4)) >> 1;                    \
      dst[n][kk] = *(const bf16x8*)&lds[buf][16384 + (rt >> 7) * 8192 +           \
                                             (rt & 127) * 64 + col];              \
    }                                                                             \
  } while (0)

#define MMAQ(qm, qn, A_, B_)                                                      \
  do {                                                                            \
    __builtin_amdgcn_s_setprio(1);                                                \
    _Pragma("unroll") for (int m = 0; m < 4; m++)                                 \
    _Pragma("unroll") for (int n = 0; n < 2; n++)                                 \
    _Pragma("unroll") for (int kk = 0; kk < 2; kk++)                              \
      acc[(qm)*4 + m][(qn)*2 + n] = __builtin_amdgcn_mfma_f32_16x16x32_bf16(      \
          A_[m][kk], B_[n][kk], acc[(qm)*4 + m][(qn)*2 + n], 0, 0, 0);            \
    __builtin_amdgcn_s_setprio(0);                                                \
  } while (0)

#define PHASE_PRE()                                                               \
  __builtin_amdgcn_s_barrier();                                                   \
  asm volatile("s_waitcnt lgkmcnt(0)" ::: "memory");                              \
  __builtin_amdgcn_sched_barrier(0)

template <int MODE>
__global__ __launch_bounds__(512, 2) void gemm256(const u16* __restrict__ A,
                                                  const u16* __restrict__ W,
                                                  void* __restrict__ Cp,
                                                  const float* __restrict__ bias,
                                                  int lda, int ldw, int ldc, int K,
                                                  int nbn, int njb,
                                                  long jsA, long jsW, long jsC, long jsB) {
  __shared__ __align__(16) u16 lds[2][32768];  // 128 KB

  const int tid = threadIdx.x;
  const int wave = tid >> 6;
  const int lane = tid & 63;
  const int wm = wave >> 2;   // 0..1: 128-row half
  const int wn = wave & 3;    // 0..3: 32-col subgroup within each B half
  const int l16 = lane & 15;
  const int kq = lane >> 4;

  // T1 bijective XCD swizzle, then batch/tile decode
  const int nwg = gridDim.x;
  int bid = blockIdx.x;
  int xcd = bid & 7, orig = bid >> 3;
  int q8 = nwg >> 3, r8 = nwg & 7;
  int wg = (xcd < r8 ? xcd * (q8 + 1) : r8 * (q8 + 1) + (xcd - r8) * q8) + orig;
  const int j = wg / njb;
  const int rem = wg - j * njb;
  const int bm = rem / nbn;
  const int bn = rem % nbn;

  const u16* Ab = A + j * jsA + (size_t)bm * BM * lda;
  const u16* Wb = W + j * jsW + (size_t)bn * BN * ldw;

  f32x4 acc[8][4];
#pragma unroll
  for (int i = 0; i < 8; i++)
#pragma unroll
    for (int n = 0; n < 4; n++) acc[i][n] = (f32x4){0.f, 0.f, 0.f, 0.f};

  // stage one half-tile: which 0=A0,1=A1,2=B0,3=B1 (base = which*8192 el)
  auto stageH = [&](int buf, int which, int k0) {
    const u16* src = (which >= 2) ? Wb : Ab;
    const int ld = (which >= 2) ? ldw : lda;
    const int h = which & 1;
#pragma unroll
    for (int r = 0; r < 2; r++) {
      int slot = r * 512 + tid;               // 1024 slots = 128 rows x 8 chunks
      int row = h * 128 + (slot >> 3);
      int col = ((slot & 7) ^ (row & 7)) * 8; // pre-swizzled source (involution)
      gload16(src + (size_t)row * ld + k0 + col, &lds[buf][which * 8192 + slot * 8]);
    }
  };

  const int nt = K / BK;
  stageH(0, 0, 0); stageH(0, 1, 0); stageH(0, 2, 0); stageH(0, 3, 0);
  asm volatile("s_waitcnt vmcnt(2)" ::: "memory");  // A0,A1,B0 landed; B1 in flight
  __builtin_amdgcn_s_barrier();

  bf16x8 a[4][2], b0[2][2], b1[2][2];
  int cur = 0;
  for (int t = 0; t < nt; ++t) {
    const bool pf = (t + 1 < nt);
    const int nb = cur ^ 1;
    const int nk = (t + 1) * BK;
    // ---- Ph0: quadrant (qm=0, qn=0) -- reads A half wm + B0 only ----
    RDA(cur, 0, a);
    RDB(cur, 0, b0);
    if (pf) stageH(nb, 0, nk);
    PHASE_PRE();
    MMAQ(0, 0, a, b0);
    if (pf) asm volatile("s_waitcnt vmcnt(2)" ::: "memory");  // B1(t) landed
    else    asm volatile("s_waitcnt vmcnt(0)" ::: "memory");
    __builtin_amdgcn_s_barrier();
    // ---- Ph1: quadrant (0,1) -- reads B1 (now resident) ----
    RDB(cur, 1, b1);
    if (pf) stageH(nb, 1, nk);
    PHASE_PRE();
    MMAQ(0, 1, a, b1);
    __builtin_amdgcn_s_barrier();
    // ---- Ph2: quadrant (1,0) ----
    RDA(cur, 1, a);
    if (pf) stageH(nb, 2, nk);
    PHASE_PRE();
    MMAQ(1, 0, a, b0);
    __builtin_amdgcn_s_barrier();
    // ---- Ph3: quadrant (1,1) -- registers only ----
    if (pf) stageH(nb, 3, nk);
    __builtin_amdgcn_s_barrier();
    MMAQ(1, 1, a, b1);
    if (pf) asm volatile("s_waitcnt vmcnt(2)" ::: "memory");  // A0,A1,B0(t+1) landed
    __builtin_amdgcn_s_barrier();
    cur ^= 1;
  }

  const int r0 = kq * 4;  // C/D: col = lane&15, row = (lane>>4)*4 + r
#pragma unroll
  for (int mf = 0; mf < 8; mf++) {
#pragma unroll
    for (int nf = 0; nf < 4; nf++) {
      int row = bm * BM + wm * 128 + mf * 16 + r0;
      int col = bn * BN + (nf >> 1) * 128 + wn * 32 + (nf & 1) * 16 + l16;
      if (MODE == 0) {
        u16* C = (u16*)Cp + j * jsC;
        float bv = bias ? bias[j * jsB + col] : 0.f;
#pragma unroll
        for (int r = 0; r < 4; r++)
          C[(size_t)(row + r) * ldc + col] = f2bf(acc[mf][nf][r] + bv);
      } else {
        float* C = (float*)Cp + j * jsC;
        float bv = bias[j * jsB + col];
#pragma unroll
        for (int r = 0; r < 4; r++)
          C[(size_t)(row + r) * ldc + col] = acc[mf][nf][r] + bv;
      }
    }
  }
}

// ---------------- attention combine (merged-projection layout) ----------------
__global__ __launch_bounds__(256) void attn_combine(const u16* __restrict__ Pq,
                                                    const u16* __restrict__ Pa,
                                                    const u16* __restrict__ Pb,
                                                    int offA, int offB,
                                                    u16* __restrict__ Oc) {
  int gw = blockIdx.x * 4 + (threadIdx.x >> 6);
  int lane = threadIdx.x & 63;
  int b = gw >> 4, h = gw & 15;
  int d = h * 64 + lane;
  size_t prow = (size_t)b * 5120;
  float q = bf2f(Pq[prow + d]);
  float k1 = bf2f(Pa[prow + offA + d]);
  float v1 = bf2f(Pa[prow + offA + 1024 + d]);
  float k2 = bf2f(Pb[prow + offB + d]);
  float v2 = bf2f(Pb[prow + offB + 1024 + d]);
  float s1 = q * k1, s2 = q * k2;
  for (int off = 32; off; off >>= 1) {
    s1 += __shfl_xor(s1, off);
    s2 += __shfl_xor(s2, off);
  }
  s1 *= 0.125f; s2 *= 0.125f;  // 1/sqrt(64)
  float m = fmaxf(s1, s2);
  float e1 = __expf(s1 - m), e2 = __expf(s2 - m);
  float rn = 1.f / (e1 + e2);
  Oc[(size_t)b * 3072 + d] = f2bf((e1 * rn) * v1 + (e2 * rn) * v2);
}

// ---------------- layernorm in place on f32 [B,1024] ----------------
__global__ __launch_bounds__(256) void layernorm_inplace(float* __restrict__ y,
                                                         const float* __restrict__ g,
                                                         const float* __restrict__ b) {
  int row = blockIdx.x, tid = threadIdx.x;
  float* yr = y + (size_t)row * E_DIM;
  f32x4 v = ((const f32x4*)yr)[tid];
  float s = v.x + v.y + v.z + v.w;
  float sq = v.x * v.x + v.y * v.y + v.z * v.z + v.w * v.w;
  for (int off = 32; off; off >>= 1) {
    s += __shfl_xor(s, off);
    sq += __shfl_xor(sq, off);
  }
  __shared__ float rs[4], rq[4];
  int wave = tid >> 6, lane = tid & 63;
  if (lane == 0) { rs[wave] = s; rq[wave] = sq; }
  __syncthreads();
  s = rs[0] + rs[1] + rs[2] + rs[3];
  sq = rq[0] + rq[1] + rq[2] + rq[3];
  float mu = s * (1.f / E_DIM);
  float var = sq * (1.f / E_DIM) - mu * mu;
  float rstd = rsqrtf(var + 1e-5f);
  f32x4 gg = ((const f32x4*)g)[tid];
  f32x4 bb = ((const f32x4*)b)[tid];
  f32x4 o;
  o.x = (v.x - mu) * rstd * gg.x + bb.x;
  o.y = (v.y - mu) * rstd * gg.y + bb.y;
  o.z = (v.z - mu) * rstd * gg.z + bb.z;
  o.w = (v.w - mu) * rstd * gg.w + bb.w;
  ((f32x4*)yr)[tid] = o;
}

extern "C" void kernel_launch(void* const* d_in, const int* in_sizes, int n_in,
                              void* d_out, int out_size, void* d_ws, size_t ws_size,
                              hipStream_t stream) {
  const float* feat[3] = {(const float*)d_in[0], (const float*)d_in[1], (const float*)d_in[2]};
  const float* w_in[3] = {(const float*)d_in[3], (const float*)d_in[7], (const float*)d_in[11]};
  const float* b_in[3] = {(const float*)d_in[4], (const float*)d_in[8], (const float*)d_in[12]};
  const float* w_out[3] = {(const float*)d_in[5], (const float*)d_in[9], (const float*)d_in[13]};
  const float* b_out[3] = {(const float*)d_in[6], (const float*)d_in[10], (const float*)d_in[14]};
  const float* w_fuse = (const float*)d_in[15];
  const float* b_fuse = (const float*)d_in[16];
  const float* ln_g = (const float*)d_in[17];
  const float* ln_b = (const float*)d_in[18];

  auto A256 = [](size_t b) { return (b + 255) & ~(size_t)255; };
  const size_t EE = (size_t)E_DIM * E_DIM;

  const size_t persist = 3 * A256(5 * EE * 2) + 3 * A256(5 * E_DIM * 4) +
                         A256(3 * EE * 2) + A256(E_DIM * 4);

  // Preferred layout: CH=2048 chunks for proj/combine + FULL Ocat (one final GEMM).
  int CH = 2048;
  bool bigOcat;
  {
    size_t need = persist + 3 * A256((size_t)CH * E_DIM * 2) +
                  3 * A256((size_t)CH * 5 * E_DIM * 2) +
                  A256((size_t)B_ROWS * 3 * E_DIM * 2);
    bigOcat = (need <= ws_size);
  }
  if (!bigOcat) {
    CH = B_ROWS;
    while (CH > 256) {
      size_t pool = 3 * A256((size_t)CH * E_DIM * 2) + 3 * A256((size_t)CH * 5 * E_DIM * 2) +
                    A256((size_t)CH * 3 * E_DIM * 2);
      if (persist + pool <= ws_size) break;
      CH -= 256;
    }
  }

  char* p = (char*)d_ws;
  auto alloc = [&](size_t bytes) {
    void* r = (void*)p;
    p += A256(bytes);
    return r;
  };

  u16* Wcat[3];
  for (int i = 0; i < 3; i++) Wcat[i] = (u16*)alloc(5 * EE * 2);
  float* bcat[3];
  for (int i = 0; i < 3; i++) bcat[i] = (float*)alloc(5 * E_DIM * 4);
  u16* Mcat = (u16*)alloc(3 * EE * 2);
  float* cb = (float*)alloc(E_DIM * 4);

  char* pool = p;

  const int oth[3][2] = {{1, 2}, {0, 2}, {0, 1}};

  // ---- stage 0: Wcat_j = [wq_j ; wkv_o0 ; wkv_o1] bf16 + bcat_j ----
  for (int j = 0; j < 3; j++) {
    int o0 = oth[j][0], o1 = oth[j][1];
    cvt_f32_bf16<<<256, 256, 0, stream>>>(w_in[j], Wcat[j], (int)(EE / 4));
    cvt_f32_bf16<<<512, 256, 0, stream>>>(w_in[o0] + EE, Wcat[j] + EE, (int)(2 * EE / 4));
    cvt_f32_bf16<<<512, 256, 0, stream>>>(w_in[o1] + EE, Wcat[j] + 3 * EE, (int)(2 * EE / 4));
    concat_bias<<<5 * E_DIM / 256, 256, 0, stream>>>(b_in[j], b_in[o0], b_in[o1], bcat[j]);
  }

  // ---- stage 1: Mcat slices + folded bias ----
  {
    u16* wfusebf = (u16*)pool;
    u16* woutT = (u16*)(pool + A256(3 * EE * 2));
    cvt_f32_bf16<<<1024, 256, 0, stream>>>(w_fuse, wfusebf, (int)(3 * EE / 4));
    dim3 tb(32, 8);
    for (int f = 0; f < 3; f++) {
      transpose_to_bf16<<<dim3(E_DIM / 32, E_DIM / 32), tb, 0, stream>>>(w_out[f], woutT, E_DIM);
      gemm256<0><<<(E_DIM / BM) * (E_DIM / BN), 512, 0, stream>>>(
          wfusebf + f * E_DIM, woutT, (void*)(Mcat + f * E_DIM), nullptr,
          3 * E_DIM, E_DIM, 3 * E_DIM, E_DIM, E_DIM / BN,
          (E_DIM / BM) * (E_DIM / BN), 0, 0, 0, 0);
    }
    fold_bias<<<E_DIM / 4, 256, 0, stream>>>(b_out[0], b_out[1], b_out[2], w_fuse, b_fuse, cb);
  }

  // ---- stage 2: chunk loop ----
  {
    char* q = pool;
    auto palloc = [&](size_t bytes) {
      void* r = (void*)q;
      q += A256(bytes);
      return r;
    };
    u16* fb0 = (u16*)palloc(3 * A256((size_t)CH * E_DIM * 2));
    u16* P0 = (u16*)palloc(3 * A256((size_t)CH * 5 * E_DIM * 2));
    u16* Ocat = (u16*)palloc(bigOcat ? (size_t)B_ROWS * 3 * E_DIM * 2
                                     : (size_t)CH * 3 * E_DIM * 2);
    const long jsA = (long)CH * E_DIM;            // fb stride (elements)
    const long jsP = (long)CH * 5 * E_DIM;        // P stride (elements)
    const long jsW = (long)(A256(5 * EE * 2) / 2);
    const long jsB = 5 * E_DIM;

    const int j1a[3] = {1, 0, 0}, j2a[3] = {2, 2, 1};
    const int offA[3] = {1024, 1024, 3072}, offB[3] = {1024, 3072, 3072};

    for (int row0 = 0; row0 < B_ROWS; row0 += CH) {
      int rows = B_ROWS - row0 < CH ? B_ROWS - row0 : CH;
      for (int j = 0; j < 3; j++)
        cvt_f32_bf16<<<1024, 256, 0, stream>>>(feat[j] + (size_t)row0 * E_DIM,
                                               fb0 + j * jsA, rows * (E_DIM / 4));
      // merged projection: P[j] = fb[j] @ Wcat_j^T + bcat_j   [rows, 5120], 3 j's in one grid
      const int njb = (rows / BM) * (5 * E_DIM / BN);
      gemm256<0><<<3 * njb, 512, 0, stream>>>(
          fb0, Wcat[0], (void*)P0, bcat[0], E_DIM, E_DIM, 5 * E_DIM, E_DIM,
          5 * E_DIM / BN, njb, jsA, jsW, jsP, jsB);
      // softmax-combine into Ocat rows [row0, row0+rows)
      u16* Oc = bigOcat ? Ocat + (size_t)row0 * 3 * E_DIM : Ocat;
      for (int m = 0; m < 3; m++)
        attn_combine<<<rows * H_N / 4, 256, 0, stream>>>(
            P0 + m * jsP, P0 + j1a[m] * jsP, P0 + j2a[m] * jsP, offA[m], offB[m],
            Oc + m * E_DIM);
      if (!bigOcat)
        gemm256<1><<<(rows / BM) * (E_DIM / BN), 512, 0, stream>>>(
            Ocat, Mcat, (void*)((float*)d_out + (size_t)row0 * E_DIM), cb,
            3 * E_DIM, 3 * E_DIM, E_DIM, 3 * E_DIM, E_DIM / BN,
            (rows / BM) * (E_DIM / BN), 0, 0, 0, 0);
    }
    if (bigOcat) {
      // one full-machine final GEMM: y = Ocat @ Mcat^T + cb  [16384, 1024], K=3072
      gemm256<1><<<(B_ROWS / BM) * (E_DIM / BN), 512, 0, stream>>>(
          Ocat, Mcat, d_out, cb, 3 * E_DIM, 3 * E_DIM, E_DIM, 3 * E_DIM,
          E_DIM / BN, (B_ROWS / BM) * (E_DIM / BN), 0, 0, 0, 0);
    }
  }

  // ---- stage 3: layernorm in place on d_out ----
  layernorm_inplace<<<B_ROWS, 256, 0, stream>>>((float*)d_out, ln_g, ln_b);
}